// Round 4
// baseline (3855.318 us; speedup 1.0000x reference)
//
#include <hip/hip_runtime.h>

#define DT 0.042f
constexpr int B = 64, L = 1024, I = 128, H = 512;

// scan decomposition: 16 batch-groups x 16 column-slices = 256 blocks (1/CU).
constexpr int NG = 16;          // batch groups
constexpr int NS = 16;          // column slices == k-chunks
constexpr int GB = B / NG;      // 4 batches per group
constexpr int SC = H / NS;      // 32 cols per slice / k per chunk
constexpr int H2H_PAD = 516;    // 512+4: rotated banks, conflict-free b128 rows
constexpr int RED_PAD = 17;     // 16+1: conflict-free partial-sum matrix

// ---------------------------------------------------------------------------
// Kernel 1: u = x @ x2h + bias -> staged into the all_states region of d_out
// ---------------------------------------------------------------------------
__global__ __launch_bounds__(256) void k_ugemm(const float* __restrict__ x,
                                               const float* __restrict__ w,
                                               const float* __restrict__ bias,
                                               float* __restrict__ u) {
    __shared__ __align__(16) float a_s[64][132];
    __shared__ __align__(16) float b_s[128][68];
    const int tx = threadIdx.x & 15;
    const int ty = threadIdx.x >> 4;
    const int row0 = blockIdx.x * 64;
    const int col0 = blockIdx.y * 64;

    for (int i = threadIdx.x; i < 64 * 32; i += 256) {
        int r = i >> 5, c4 = (i & 31) << 2;
        *(float4*)&a_s[r][c4] = *(const float4*)(x + (size_t)(row0 + r) * I + c4);
    }
    for (int i = threadIdx.x; i < 128 * 16; i += 256) {
        int k = i >> 4, c4 = (i & 15) << 2;
        *(float4*)&b_s[k][c4] = *(const float4*)(w + (size_t)k * H + col0 + c4);
    }
    __syncthreads();

    float acc[4][4] = {};
    for (int k = 0; k < I; k += 4) {
        float a4[4][4], b4[4][4];
        #pragma unroll
        for (int i = 0; i < 4; ++i) *(float4*)a4[i] = *(const float4*)&a_s[ty * 4 + i][k];
        #pragma unroll
        for (int kk = 0; kk < 4; ++kk) *(float4*)b4[kk] = *(const float4*)&b_s[k + kk][tx * 4];
        #pragma unroll
        for (int i = 0; i < 4; ++i)
            #pragma unroll
            for (int kk = 0; kk < 4; ++kk)
                #pragma unroll
                for (int j = 0; j < 4; ++j)
                    acc[i][j] += a4[i][kk] * b4[kk][j];
    }
    float4 bv = *(const float4*)&bias[col0 + tx * 4];
    #pragma unroll
    for (int i = 0; i < 4; ++i) {
        size_t r = (size_t)(row0 + ty * 4 + i);
        float4 o;
        o.x = acc[i][0] + bv.x; o.y = acc[i][1] + bv.y;
        o.z = acc[i][2] + bv.z; o.w = acc[i][3] + bv.w;
        *(float4*)&u[r * H + col0 + tx * 4] = o;
    }
}

// ---------------------------------------------------------------------------
// Kernel 2: the scan, half-wave dataflow.
// Chunk kc's 32 consumer threads are one half-wave and poll ONLY producer
// slice kc's 128 tagged qwords (4 each), fill their private hy_c chunk, and
// run their partial matmul immediately (wave lockstep + in-order DS pipe =
// no barrier). ONE block barrier/step guards red write->read; red is parity
// double-buffered; readers pass the next step's barrier before the same
// parity is rewritten. Cross-block slot reuse safe as before (publish of t+1
// implies all peers consumed t-1).
// ---------------------------------------------------------------------------
__global__ __launch_bounds__(512) void k_scan(float* __restrict__ su,
                                              const float* __restrict__ h2h,
                                              const float* __restrict__ gamma,
                                              const float* __restrict__ epsv,
                                              unsigned long long* __restrict__ wsq,
                                              float* __restrict__ hyfin) {
    __shared__ __align__(16) float h2h_t[SC * H2H_PAD];        // [cc][k]  66 KiB
    __shared__ __align__(16) float hy_c[NS * GB * SC];         // [kc][b][kk] 8 KiB
    __shared__ __align__(16) float red[2][GB * SC * RED_PAD];  // [p][out][kc] 17.4 KiB
    const int tid = threadIdx.x;
    const int g = blockIdx.x & 15;    // group (stride-16 members -> same XCD heuristic)
    const int s = blockIdx.x >> 4;    // column slice
    const int b0 = g * GB, c0 = s * SC;

    // transposed fill: h2h_t[cc][k] = h2h[k][c0+cc] (coalesced global reads)
    for (int i = tid; i < H * SC; i += 512) {
        int k = i >> 5, c = i & 31;
        h2h_t[c * H2H_PAD + k] = h2h[(size_t)k * H + c0 + c];
    }

    const int cc = tid & 31, kc = tid >> 5;       // compute role
    const int pb = cc >> 3, pj = cc & 7;          // poll role within chunk
    const int scc = tid & 31, sb = (tid >> 5) & 3;  // state role (tid < 128)
    const int sc_ = c0 + scc;
    float gam = 0.f, ep = 0.f;
    float* su_p = nullptr;
    if (tid < 128) {
        gam = gamma[sc_]; ep = epsv[sc_];
        su_p = su + (size_t)(b0 + sb) * L * H + sc_;
    }
    unsigned long long* pollA = wsq + (size_t)(b0 + pb) * H + kc * SC + pj * 4;
    unsigned long long* pollB = pollA + (size_t)B * H;
    unsigned long long* dstA  = wsq + (size_t)(b0 + sb) * H + sc_;
    unsigned long long* dstB  = dstA + (size_t)B * H;

    const float* hrow = h2h_t + cc * H2H_PAD + kc * SC;  // own h2h column, own chunk
    const float* hyrow = hy_c + kc * (GB * SC);          // own chunk hy
    float* myhy = hy_c + kc * (GB * SC) + pb * SC + pj * 4;

    float hy = 0.f, hz = 0.f;
    __syncthreads();                              // h2h_t ready

    for (int t = 0; t < L; ++t) {
        float uval = 0.f;
        if (tid < 128) uval = *su_p;              // u[t] prefetch, hides under poll

        if (t > 0) {
            unsigned long long* src = (t & 1) ? pollB : pollA;
            unsigned long long w[4];
            #pragma unroll
            for (int j = 0; j < 4; ++j)
                w[j] = __hip_atomic_load(src + j, __ATOMIC_RELAXED,
                                         __HIP_MEMORY_SCOPE_AGENT);
            const unsigned tg = (unsigned)t;
            bool done = false;
            while (!done) {
                done = true;
                #pragma unroll
                for (int j = 0; j < 4; ++j)
                    if ((unsigned)(w[j] >> 32) != tg) {
                        w[j] = __hip_atomic_load(src + j, __ATOMIC_RELAXED,
                                                 __HIP_MEMORY_SCOPE_AGENT);
                        done = false;
                    }
            }
            float4 hv;
            hv.x = __uint_as_float((unsigned)w[0]);
            hv.y = __uint_as_float((unsigned)w[1]);
            hv.z = __uint_as_float((unsigned)w[2]);
            hv.w = __uint_as_float((unsigned)w[3]);
            *(float4*)myhy = hv;                  // fill own chunk (half-wave private)
        } else {
            *(float4*)myhy = float4{0.f, 0.f, 0.f, 0.f};
        }
        // no barrier: consumers of this chunk are this same half-wave (lockstep,
        // in-order per-wave DS pipeline orders the write before the reads)

        // partial matmul over own chunk: acc[b] = sum_k hy[b][k]*h2h[k][cc]
        float acc0 = 0.f, acc1 = 0.f, acc2 = 0.f, acc3 = 0.f;
        #pragma unroll
        for (int kk = 0; kk < SC; kk += 4) {
            const float4 hw = *(const float4*)(hrow + kk);          // private, b128
            const float4 y0 = *(const float4*)(hyrow + 0 * SC + kk); // broadcast
            const float4 y1 = *(const float4*)(hyrow + 1 * SC + kk);
            const float4 y2 = *(const float4*)(hyrow + 2 * SC + kk);
            const float4 y3 = *(const float4*)(hyrow + 3 * SC + kk);
            acc0 += hw.x * y0.x + hw.y * y0.y + hw.z * y0.z + hw.w * y0.w;
            acc1 += hw.x * y1.x + hw.y * y1.y + hw.z * y1.z + hw.w * y1.w;
            acc2 += hw.x * y2.x + hw.y * y2.y + hw.z * y2.z + hw.w * y2.w;
            acc3 += hw.x * y3.x + hw.y * y3.y + hw.z * y3.z + hw.w * y3.w;
        }
        float* rp = red[t & 1];
        rp[(0 * SC + cc) * RED_PAD + kc] = acc0;
        rp[(1 * SC + cc) * RED_PAD + kc] = acc1;
        rp[(2 * SC + cc) * RED_PAD + kc] = acc2;
        rp[(3 * SC + cc) * RED_PAD + kc] = acc3;
        __syncthreads();                          // THE one barrier per step

        if (tid < 128) {
            const float* rq = red[t & 1] + (sb * SC + scc) * RED_PAD;
            float m0 = rq[0] + rq[4] + rq[8] + rq[12];
            float m1 = rq[1] + rq[5] + rq[9] + rq[13];
            float m2 = rq[2] + rq[6] + rq[10] + rq[14];
            float m3 = rq[3] + rq[7] + rq[11] + rq[15];
            const float xx = uval + ((m0 + m1) + (m2 + m3));
            const float cx = fminf(fmaxf(xx, -10.f), 10.f);  // tanh via exp, clamped
            const float e2 = __expf(2.f * cx);
            const float th = (e2 - 1.f) / (e2 + 1.f);
            hz += DT * (th - gam * hy - ep * hz);
            hy += DT * hz;
            // publish FIRST (critical path), bookkeeping after
            const unsigned long long wq =
                ((unsigned long long)(unsigned)(t + 1) << 32) | __float_as_uint(hy);
            __hip_atomic_store(((t + 1) & 1) ? dstB : dstA, wq,
                               __ATOMIC_RELAXED, __HIP_MEMORY_SCOPE_AGENT);
            *su_p = hy;                           // all_states[b][t][c]
            su_p += H;
            if (t == L - 1) hyfin[(size_t)(b0 + sb) * H + sc_] = hy;
        }
    }
}

extern "C" void kernel_launch(void* const* d_in, const int* in_sizes, int n_in,
                              void* d_out, int out_size, void* d_ws, size_t ws_size,
                              hipStream_t stream) {
    const float* x     = (const float*)d_in[0];
    const float* x2h   = (const float*)d_in[1];
    const float* h2h   = (const float*)d_in[2];
    const float* bias  = (const float*)d_in[3];
    const float* gamma = (const float*)d_in[4];
    const float* epsv  = (const float*)d_in[5];
    float* states = (float*)d_out;                      // (B, L, H)
    float* hyfin  = states + (size_t)B * L * H;         // (B, H)

    unsigned long long* wsq = (unsigned long long*)d_ws;  // 2 x (B*H) tagged qwords

    hipMemsetAsync(d_ws, 0, 2ull * B * H * 8, stream);  // tag 0 != any awaited t>=1
    dim3 g1(B * L / 64, H / 64);
    k_ugemm<<<g1, 256, 0, stream>>>(x, x2h, bias, states);
    k_scan<<<NG * NS, 512, 0, stream>>>(states, h2h, gamma, epsv, wsq, hyfin);
}

// Round 5
// 1869.894 us; speedup vs baseline: 2.0618x; 2.0618x over previous
//
#include <hip/hip_runtime.h>

#define DT 0.042f
constexpr int B = 64, L = 1024, I = 128, H = 512;

// scan decomposition: 32 batch-groups x 8 column-slices = 256 blocks (1/CU).
// Group members = {g + 32*s}: same blockIdx%8 -> same presumed XCD (perf only).
constexpr int NG = 32;          // batch groups
constexpr int NS = 8;           // column slices == k-chunks
constexpr int GB = B / NG;      // 2 batches per group
constexpr int SC = H / NS;      // 64 cols per slice / k per chunk

// ---------------------------------------------------------------------------
// Kernel 1: u = x @ x2h + bias -> staged into the all_states region of d_out
// ---------------------------------------------------------------------------
__global__ __launch_bounds__(256) void k_ugemm(const float* __restrict__ x,
                                               const float* __restrict__ w,
                                               const float* __restrict__ bias,
                                               float* __restrict__ u) {
    __shared__ __align__(16) float a_s[64][132];
    __shared__ __align__(16) float b_s[128][68];
    const int tx = threadIdx.x & 15;
    const int ty = threadIdx.x >> 4;
    const int row0 = blockIdx.x * 64;
    const int col0 = blockIdx.y * 64;

    for (int i = threadIdx.x; i < 64 * 32; i += 256) {
        int r = i >> 5, c4 = (i & 31) << 2;
        *(float4*)&a_s[r][c4] = *(const float4*)(x + (size_t)(row0 + r) * I + c4);
    }
    for (int i = threadIdx.x; i < 128 * 16; i += 256) {
        int k = i >> 4, c4 = (i & 15) << 2;
        *(float4*)&b_s[k][c4] = *(const float4*)(w + (size_t)k * H + col0 + c4);
    }
    __syncthreads();

    float acc[4][4] = {};
    for (int k = 0; k < I; k += 4) {
        float a4[4][4], b4[4][4];
        #pragma unroll
        for (int i = 0; i < 4; ++i) *(float4*)a4[i] = *(const float4*)&a_s[ty * 4 + i][k];
        #pragma unroll
        for (int kk = 0; kk < 4; ++kk) *(float4*)b4[kk] = *(const float4*)&b_s[k + kk][tx * 4];
        #pragma unroll
        for (int i = 0; i < 4; ++i)
            #pragma unroll
            for (int kk = 0; kk < 4; ++kk)
                #pragma unroll
                for (int j = 0; j < 4; ++j)
                    acc[i][j] += a4[i][kk] * b4[kk][j];
    }
    float4 bv = *(const float4*)&bias[col0 + tx * 4];
    #pragma unroll
    for (int i = 0; i < 4; ++i) {
        size_t r = (size_t)(row0 + ty * 4 + i);
        float4 o;
        o.x = acc[i][0] + bv.x; o.y = acc[i][1] + bv.y;
        o.z = acc[i][2] + bv.z; o.w = acc[i][3] + bv.w;
        *(float4*)&u[r * H + col0 + tx * 4] = o;
    }
}

// ---------------------------------------------------------------------------
// Kernel 2: the scan — round-3 phase-locked skeleton, register-resident h2h.
// Exchange words are (tag<<32 | float_bits) qwords in d_ws, double-buffered by
// step parity; publish = relaxed agent-scope atomic store; consume = each
// thread polls its 2 qwords until tag==t (data arrival IS the sync), then
// barrier -> matmul (h2h from 64 VGPRs, hy via wave-broadcast LDS reads) ->
// barrier -> reduce+update+publish -> barrier. Buffer-reuse safety: publish
// of t+1 into slot (t+1)&1 implies all peers consumed t-1 (induction as R3).
// ---------------------------------------------------------------------------
__global__ __launch_bounds__(512) void k_scan(float* __restrict__ su,
                                              const float* __restrict__ h2h,
                                              const float* __restrict__ gamma,
                                              const float* __restrict__ epsv,
                                              unsigned long long* __restrict__ wsq,
                                              float* __restrict__ hyfin) {
    __shared__ __align__(16) float hy_s[GB * H];        // [b][k]       4 KiB
    __shared__ __align__(16) float red[NS * GB * SC];   // [kc][b][cc]  4 KiB
    const int tid = threadIdx.x;
    const int g = blockIdx.x & 31;    // group (members stride-32 -> same XCD%8)
    const int s = blockIdx.x >> 5;    // column slice 0..7
    const int b0 = g * GB, c0 = s * SC;

    const int cc = tid & 63, kc = tid >> 6;       // compute map: 64 cols x 8 k-chunks
    const int scc = tid & 63, sb = (tid >> 6) & 1;  // state map (tid < 128)
    const int sc_ = c0 + scc;

    // h2h chunk in registers: hreg[kk] = h2h[kc*64+kk][c0+cc]  (64 VGPRs)
    float hreg[64];
    {
        const float* hp = h2h + (size_t)(kc * 64) * H + c0 + cc;
        #pragma unroll
        for (int kk = 0; kk < 64; ++kk) hreg[kk] = hp[(size_t)kk * H];
    }

    float gam = 0.f, ep = 0.f;
    float* su_p = nullptr;
    if (tid < 128) {
        gam = gamma[sc_]; ep = epsv[sc_];
        su_p = su + (size_t)(b0 + sb) * L * H + sc_;
    }
    // poll: this thread's 2 qwords of the group's 1024-qword hy region
    unsigned long long* pollA = wsq + (size_t)b0 * H + (size_t)tid * 2;
    unsigned long long* pollB = pollA + (size_t)B * H;
    unsigned long long* dstA  = wsq + (size_t)(b0 + sb) * H + sc_;
    unsigned long long* dstB  = dstA + (size_t)B * H;

    float hy = 0.f, hz = 0.f;
    __syncthreads();

    for (int t = 0; t < L; ++t) {
        float uval = 0.f;
        if (tid < 128) uval = *su_p;              // u[t] prefetch, hides under poll

        if (t > 0) {
            unsigned long long* src = (t & 1) ? pollB : pollA;
            unsigned long long w0 = __hip_atomic_load(src + 0, __ATOMIC_RELAXED,
                                                      __HIP_MEMORY_SCOPE_AGENT);
            unsigned long long w1 = __hip_atomic_load(src + 1, __ATOMIC_RELAXED,
                                                      __HIP_MEMORY_SCOPE_AGENT);
            const unsigned tg = (unsigned)t;
            while ((unsigned)(w0 >> 32) != tg || (unsigned)(w1 >> 32) != tg) {
                if ((unsigned)(w0 >> 32) != tg)
                    w0 = __hip_atomic_load(src + 0, __ATOMIC_RELAXED,
                                           __HIP_MEMORY_SCOPE_AGENT);
                if ((unsigned)(w1 >> 32) != tg)
                    w1 = __hip_atomic_load(src + 1, __ATOMIC_RELAXED,
                                           __HIP_MEMORY_SCOPE_AGENT);
            }
            float2 hv;
            hv.x = __uint_as_float((unsigned)w0);
            hv.y = __uint_as_float((unsigned)w1);
            *(float2*)&hy_s[tid * 2] = hv;
        } else {
            *(float2*)&hy_s[tid * 2] = float2{0.f, 0.f};
        }
        __syncthreads();                          // (1) hy_s ready — phase lock

        // partial matmul: acc[b] = sum_{kk} hreg[kk] * hy[b][kc*64+kk]
        // hy_s reads are full-wave broadcasts (address uniform across lanes).
        float acc0 = 0.f, acc1 = 0.f;
        const int k0 = kc * 64;
        #pragma unroll
        for (int q = 0; q < 16; ++q) {
            const float4 y0 = *(const float4*)&hy_s[0 * H + k0 + q * 4];
            const float4 y1 = *(const float4*)&hy_s[1 * H + k0 + q * 4];
            acc0 += hreg[q * 4 + 0] * y0.x + hreg[q * 4 + 1] * y0.y
                  + hreg[q * 4 + 2] * y0.z + hreg[q * 4 + 3] * y0.w;
            acc1 += hreg[q * 4 + 0] * y1.x + hreg[q * 4 + 1] * y1.y
                  + hreg[q * 4 + 2] * y1.z + hreg[q * 4 + 3] * y1.w;
        }
        red[kc * (GB * SC) + 0 * SC + cc] = acc0;
        red[kc * (GB * SC) + 1 * SC + cc] = acc1;
        __syncthreads();                          // (2) partials ready

        if (tid < 128) {
            float m0 = 0.f, m1 = 0.f, m2 = 0.f, m3 = 0.f;
            const float* rq = red + sb * SC + scc;
            m0 = rq[0 * 128] + rq[1 * 128];
            m1 = rq[2 * 128] + rq[3 * 128];
            m2 = rq[4 * 128] + rq[5 * 128];
            m3 = rq[6 * 128] + rq[7 * 128];
            const float xx = uval + ((m0 + m1) + (m2 + m3));
            const float cx = fminf(fmaxf(xx, -10.f), 10.f);  // tanh via exp, clamped
            const float e2 = __expf(2.f * cx);
            const float th = (e2 - 1.f) / (e2 + 1.f);
            hz += DT * (th - gam * hy - ep * hz);
            hy += DT * hz;
            // publish FIRST (critical path), bookkeeping after
            const unsigned long long wq =
                ((unsigned long long)(unsigned)(t + 1) << 32) | __float_as_uint(hy);
            __hip_atomic_store(((t + 1) & 1) ? dstB : dstA, wq,
                               __ATOMIC_RELAXED, __HIP_MEMORY_SCOPE_AGENT);
            *su_p = hy;                           // all_states[b][t][c]
            su_p += H;
            if (t == L - 1) hyfin[(size_t)(b0 + sb) * H + sc_] = hy;
        }
        __syncthreads();                          // (3) red/hy_s safe to overwrite
    }
}

extern "C" void kernel_launch(void* const* d_in, const int* in_sizes, int n_in,
                              void* d_out, int out_size, void* d_ws, size_t ws_size,
                              hipStream_t stream) {
    const float* x     = (const float*)d_in[0];
    const float* x2h   = (const float*)d_in[1];
    const float* h2h   = (const float*)d_in[2];
    const float* bias  = (const float*)d_in[3];
    const float* gamma = (const float*)d_in[4];
    const float* epsv  = (const float*)d_in[5];
    float* states = (float*)d_out;                      // (B, L, H)
    float* hyfin  = states + (size_t)B * L * H;         // (B, H)

    unsigned long long* wsq = (unsigned long long*)d_ws;  // 2 x (B*H) tagged qwords

    hipMemsetAsync(d_ws, 0, 2ull * B * H * 8, stream);  // tag 0 != any awaited t>=1
    dim3 g1(B * L / 64, H / 64);
    k_ugemm<<<g1, 256, 0, stream>>>(x, x2h, bias, states);
    k_scan<<<NG * NS, 512, 0, stream>>>(states, h2h, gamma, epsv, wsq, hyfin);
}

// Round 6
// 1860.970 us; speedup vs baseline: 2.0717x; 1.0048x over previous
//
#include <hip/hip_runtime.h>

#define DT 0.042f
constexpr int B = 64, L = 1024, I = 128, H = 512;

// scan decomposition: 32 batch-groups x 8 column-slices = 256 blocks (1/CU).
// Group members = {g + 32*s}: same blockIdx%8 -> same presumed XCD (perf only).
constexpr int NG = 32;          // batch groups
constexpr int NS = 8;           // column slices == k-chunks
constexpr int GB = B / NG;      // 2 batches per group
constexpr int SC = H / NS;      // 64 cols per slice / k per chunk

// ---------------------------------------------------------------------------
// Kernel 1: u = x @ x2h + bias -> staged into the all_states region of d_out
// ---------------------------------------------------------------------------
__global__ __launch_bounds__(256) void k_ugemm(const float* __restrict__ x,
                                               const float* __restrict__ w,
                                               const float* __restrict__ bias,
                                               float* __restrict__ u) {
    __shared__ __align__(16) float a_s[64][132];
    __shared__ __align__(16) float b_s[128][68];
    const int tx = threadIdx.x & 15;
    const int ty = threadIdx.x >> 4;
    const int row0 = blockIdx.x * 64;
    const int col0 = blockIdx.y * 64;

    for (int i = threadIdx.x; i < 64 * 32; i += 256) {
        int r = i >> 5, c4 = (i & 31) << 2;
        *(float4*)&a_s[r][c4] = *(const float4*)(x + (size_t)(row0 + r) * I + c4);
    }
    for (int i = threadIdx.x; i < 128 * 16; i += 256) {
        int k = i >> 4, c4 = (i & 15) << 2;
        *(float4*)&b_s[k][c4] = *(const float4*)(w + (size_t)k * H + col0 + c4);
    }
    __syncthreads();

    float acc[4][4] = {};
    for (int k = 0; k < I; k += 4) {
        float a4[4][4], b4[4][4];
        #pragma unroll
        for (int i = 0; i < 4; ++i) *(float4*)a4[i] = *(const float4*)&a_s[ty * 4 + i][k];
        #pragma unroll
        for (int kk = 0; kk < 4; ++kk) *(float4*)b4[kk] = *(const float4*)&b_s[k + kk][tx * 4];
        #pragma unroll
        for (int i = 0; i < 4; ++i)
            #pragma unroll
            for (int kk = 0; kk < 4; ++kk)
                #pragma unroll
                for (int j = 0; j < 4; ++j)
                    acc[i][j] += a4[i][kk] * b4[kk][j];
    }
    float4 bv = *(const float4*)&bias[col0 + tx * 4];
    #pragma unroll
    for (int i = 0; i < 4; ++i) {
        size_t r = (size_t)(row0 + ty * 4 + i);
        float4 o;
        o.x = acc[i][0] + bv.x; o.y = acc[i][1] + bv.y;
        o.z = acc[i][2] + bv.z; o.w = acc[i][3] + bv.w;
        *(float4*)&u[r * H + col0 + tx * 4] = o;
    }
}

// ---------------------------------------------------------------------------
// Kernel 2: the scan — round-5 structure, h2h chunk PINNED in VGPRs.
// __launch_bounds__(512, 2): 2 waves/EU -> VGPR cap 256; grid is 1 block/CU
// so the extra registers are free (occupancy is grid-limited).
// asm pin after the fill forces hreg into distinct VGPRs (round-5 counters
// showed VGPR_Count=52 => compiler was re-loading h2h from L2 every step).
// ---------------------------------------------------------------------------
__global__ __launch_bounds__(512, 2) void k_scan(float* __restrict__ su,
                                              const float* __restrict__ h2h,
                                              const float* __restrict__ gamma,
                                              const float* __restrict__ epsv,
                                              unsigned long long* __restrict__ wsq,
                                              float* __restrict__ hyfin) {
    __shared__ __align__(16) float hy_s[GB * H];        // [b][k]       4 KiB
    __shared__ __align__(16) float red[NS * GB * SC];   // [kc][b][cc]  4 KiB
    const int tid = threadIdx.x;
    const int g = blockIdx.x & 31;    // group (members stride-32 -> same XCD%8)
    const int s = blockIdx.x >> 5;    // column slice 0..7
    const int b0 = g * GB, c0 = s * SC;

    const int cc = tid & 63, kc = tid >> 6;       // compute map: 64 cols x 8 k-chunks
    const int scc = tid & 63, sb = (tid >> 6) & 1;  // state map (tid < 128)
    const int sc_ = c0 + scc;

    // h2h chunk in registers: hreg[kk] = h2h[kc*64+kk][c0+cc]  (64 VGPRs)
    float hreg[64];
    {
        const float* hp = h2h + (size_t)(kc * 64) * H + c0 + cc;
        #pragma unroll
        for (int kk = 0; kk < 64; ++kk) hreg[kk] = hp[(size_t)kk * H];
        #pragma unroll
        for (int kk = 0; kk < 64; ++kk) asm volatile("" : "+v"(hreg[kk]));  // pin
    }

    float gam = 0.f, ep = 0.f;
    float* su_p = nullptr;
    if (tid < 128) {
        gam = gamma[sc_]; ep = epsv[sc_];
        su_p = su + (size_t)(b0 + sb) * L * H + sc_;
    }
    // poll: this thread's 2 qwords of the group's 1024-qword hy region
    unsigned long long* pollA = wsq + (size_t)b0 * H + (size_t)tid * 2;
    unsigned long long* pollB = pollA + (size_t)B * H;
    unsigned long long* dstA  = wsq + (size_t)(b0 + sb) * H + sc_;
    unsigned long long* dstB  = dstA + (size_t)B * H;

    float hy = 0.f, hz = 0.f;
    __syncthreads();

    for (int t = 0; t < L; ++t) {
        float uval = 0.f;
        if (tid < 128) uval = *su_p;              // u[t] prefetch, hides under poll

        if (t > 0) {
            unsigned long long* src = (t & 1) ? pollB : pollA;
            unsigned long long w0 = __hip_atomic_load(src + 0, __ATOMIC_RELAXED,
                                                      __HIP_MEMORY_SCOPE_AGENT);
            unsigned long long w1 = __hip_atomic_load(src + 1, __ATOMIC_RELAXED,
                                                      __HIP_MEMORY_SCOPE_AGENT);
            const unsigned tg = (unsigned)t;
            while ((unsigned)(w0 >> 32) != tg || (unsigned)(w1 >> 32) != tg) {
                if ((unsigned)(w0 >> 32) != tg)
                    w0 = __hip_atomic_load(src + 0, __ATOMIC_RELAXED,
                                           __HIP_MEMORY_SCOPE_AGENT);
                if ((unsigned)(w1 >> 32) != tg)
                    w1 = __hip_atomic_load(src + 1, __ATOMIC_RELAXED,
                                           __HIP_MEMORY_SCOPE_AGENT);
            }
            float2 hv;
            hv.x = __uint_as_float((unsigned)w0);
            hv.y = __uint_as_float((unsigned)w1);
            *(float2*)&hy_s[tid * 2] = hv;
        } else {
            *(float2*)&hy_s[tid * 2] = float2{0.f, 0.f};
        }
        __syncthreads();                          // (1) hy_s ready — phase lock

        // partial matmul: acc[b] = sum_{kk} hreg[kk] * hy[b][kc*64+kk]
        // hy_s reads are full-wave broadcasts (address uniform across lanes).
        float acc0 = 0.f, acc1 = 0.f;
        const int k0 = kc * 64;
        #pragma unroll
        for (int q = 0; q < 16; ++q) {
            const float4 y0 = *(const float4*)&hy_s[0 * H + k0 + q * 4];
            const float4 y1 = *(const float4*)&hy_s[1 * H + k0 + q * 4];
            acc0 += hreg[q * 4 + 0] * y0.x + hreg[q * 4 + 1] * y0.y
                  + hreg[q * 4 + 2] * y0.z + hreg[q * 4 + 3] * y0.w;
            acc1 += hreg[q * 4 + 0] * y1.x + hreg[q * 4 + 1] * y1.y
                  + hreg[q * 4 + 2] * y1.z + hreg[q * 4 + 3] * y1.w;
        }
        red[kc * (GB * SC) + 0 * SC + cc] = acc0;
        red[kc * (GB * SC) + 1 * SC + cc] = acc1;
        __syncthreads();                          // (2) partials ready

        if (tid < 128) {
            const float* rq = red + sb * SC + scc;
            float m0 = rq[0 * 128] + rq[1 * 128];
            float m1 = rq[2 * 128] + rq[3 * 128];
            float m2 = rq[4 * 128] + rq[5 * 128];
            float m3 = rq[6 * 128] + rq[7 * 128];
            const float xx = uval + ((m0 + m1) + (m2 + m3));
            const float cx = fminf(fmaxf(xx, -10.f), 10.f);  // tanh via exp, clamped
            const float e2 = __expf(2.f * cx);
            const float th = (e2 - 1.f) / (e2 + 1.f);
            hz += DT * (th - gam * hy - ep * hz);
            hy += DT * hz;
            // publish FIRST (critical path), bookkeeping after
            const unsigned long long wq =
                ((unsigned long long)(unsigned)(t + 1) << 32) | __float_as_uint(hy);
            __hip_atomic_store(((t + 1) & 1) ? dstB : dstA, wq,
                               __ATOMIC_RELAXED, __HIP_MEMORY_SCOPE_AGENT);
            *su_p = hy;                           // all_states[b][t][c]
            su_p += H;
            if (t == L - 1) hyfin[(size_t)(b0 + sb) * H + sc_] = hy;
        }
        __syncthreads();                          // (3) red/hy_s safe to overwrite
    }
}

extern "C" void kernel_launch(void* const* d_in, const int* in_sizes, int n_in,
                              void* d_out, int out_size, void* d_ws, size_t ws_size,
                              hipStream_t stream) {
    const float* x     = (const float*)d_in[0];
    const float* x2h   = (const float*)d_in[1];
    const float* h2h   = (const float*)d_in[2];
    const float* bias  = (const float*)d_in[3];
    const float* gamma = (const float*)d_in[4];
    const float* epsv  = (const float*)d_in[5];
    float* states = (float*)d_out;                      // (B, L, H)
    float* hyfin  = states + (size_t)B * L * H;         // (B, H)

    unsigned long long* wsq = (unsigned long long*)d_ws;  // 2 x (B*H) tagged qwords

    hipMemsetAsync(d_ws, 0, 2ull * B * H * 8, stream);  // tag 0 != any awaited t>=1
    dim3 g1(B * L / 64, H / 64);
    k_ugemm<<<g1, 256, 0, stream>>>(x, x2h, bias, states);
    k_scan<<<NG * NS, 512, 0, stream>>>(states, h2h, gamma, epsv, wsq, hyfin);
}